// Round 9
// baseline (1238.612 us; speedup 1.0000x reference)
//
#include <hip/hip_runtime.h>
#include <cstdint>
#include <cstddef>

// GPT-2: L=4, B=2, S=1024, D=768, H=12, HD=64, FF=3072, V=50257
#define D_MODEL 768
#define NHEAD   12
#define SEQ     1024
#define NTOK    2048
#define FFDIM   3072
#define NLAYER  4
#define VOCAB   50257
#define QKVD    2304

typedef float f32x4 __attribute__((ext_vector_type(4)));
typedef __bf16 bf16x8 __attribute__((ext_vector_type(8)));

__device__ __forceinline__ unsigned short f2bf(float f) {
  unsigned int u = __float_as_uint(f);
  return (unsigned short)((u + 0x7FFFu + ((u >> 16) & 1u)) >> 16);
}

// ---------------- fp32 -> bf16 bulk convert, all 5 weights in one launch ----
__global__ __launch_bounds__(256) void k_cvt5(const float* __restrict__ s0, unsigned short* __restrict__ d0, int n0,
                                              const float* __restrict__ s1, unsigned short* __restrict__ d1, int n1,
                                              const float* __restrict__ s2, unsigned short* __restrict__ d2, int n2,
                                              const float* __restrict__ s3, unsigned short* __restrict__ d3, int n3,
                                              const float* __restrict__ s4, unsigned short* __restrict__ d4, int n4) {
  int off = blockIdx.x * 256 + threadIdx.x;
  const float* s; unsigned short* d;
  if (off < n0) { s = s0; d = d0; }
  else { off -= n0; if (off < n1) { s = s1; d = d1; }
  else { off -= n1; if (off < n2) { s = s2; d = d2; }
  else { off -= n2; if (off < n3) { s = s3; d = d3; }
  else { off -= n3; if (off >= n4) return; s = s4; d = d4; } } } }
  float4 a = ((const float4*)s)[2 * off], b = ((const float4*)s)[2 * off + 1];
  union { unsigned short u[8]; uint4 v; } r;
  r.u[0] = f2bf(a.x); r.u[1] = f2bf(a.y); r.u[2] = f2bf(a.z); r.u[3] = f2bf(a.w);
  r.u[4] = f2bf(b.x); r.u[5] = f2bf(b.y); r.u[6] = f2bf(b.z); r.u[7] = f2bf(b.w);
  ((uint4*)d)[off] = r.v;
}

// ---------------- embedding: x = tok_emb[ids] + pos_emb (fp32) -------------
__global__ __launch_bounds__(256) void k_embed(const int* __restrict__ ids,
                                               const float* __restrict__ tok,
                                               const float* __restrict__ pos,
                                               float* __restrict__ x) {
  int gid = blockIdx.x * 256 + threadIdx.x;   // NTOK*192 float4s
  int t = gid / 192, f = gid - t * 192;
  int id = ids[t];
  float4 a = ((const float4*)tok)[(size_t)id * 192 + f];
  float4 b = ((const float4*)pos)[(size_t)(t & (SEQ - 1)) * 192 + f];
  float4 o; o.x = a.x + b.x; o.y = a.y + b.y; o.z = a.z + b.z; o.w = a.w + b.w;
  ((float4*)x)[gid] = o;
}

// ---------------- LayerNorm: fp32 in, bf16 out ----------------
__global__ __launch_bounds__(256) void k_ln(const float* __restrict__ x,
                                            const float* __restrict__ w,
                                            const float* __restrict__ b,
                                            unsigned short* __restrict__ out) {
  __shared__ float red[256];
  int row = blockIdx.x, tid = threadIdx.x;
  const float* xr = x + (size_t)row * D_MODEL;
  float v0 = xr[tid], v1 = xr[tid + 256], v2 = xr[tid + 512];
  red[tid] = v0 + v1 + v2;
  __syncthreads();
  for (int o = 128; o > 0; o >>= 1) { if (tid < o) red[tid] += red[tid + o]; __syncthreads(); }
  float mean = red[0] * (1.0f / 768.0f);
  __syncthreads();
  float d0 = v0 - mean, d1 = v1 - mean, d2 = v2 - mean;
  red[tid] = d0 * d0 + d1 * d1 + d2 * d2;
  __syncthreads();
  for (int o = 128; o > 0; o >>= 1) { if (tid < o) red[tid] += red[tid + o]; __syncthreads(); }
  float rstd = rsqrtf(red[0] * (1.0f / 768.0f) + 1e-5f);
  unsigned short* orow = out + (size_t)row * D_MODEL;
  orow[tid]       = f2bf(d0 * rstd * w[tid]       + b[tid]);
  orow[tid + 256] = f2bf(d1 * rstd * w[tid + 256] + b[tid + 256]);
  orow[tid + 512] = f2bf(d2 * rstd * w[tid + 512] + b[tid + 512]);
}

// ---------------- V transpose: vt[b*768 + hd][s] = V[b,s,hd] ----------------
__global__ __launch_bounds__(256) void k_vt(const unsigned short* __restrict__ qkv,
                                            unsigned short* __restrict__ vt) {
  __shared__ unsigned short t[64][80];
  int bid = blockIdx.x;                       // 2*12*16 = 384
  int st = bid & 15, h = (bid >> 4) % NHEAD, b = bid / (16 * NHEAD);
  int tid = threadIdx.x;
  int r = tid >> 2, cq = (tid & 3) * 16;
  const unsigned short* src =
      qkv + (size_t)(b * SEQ + st * 64 + r) * QKVD + 2 * D_MODEL + h * 64 + cq;
  *(uint4*)&t[r][cq] = *(const uint4*)src;
  *(uint4*)&t[r][cq + 8] = *(const uint4*)(src + 8);
  __syncthreads();
  int d = r, j0 = cq;
  unsigned short* dst = vt + ((size_t)(b * D_MODEL) + h * 64 + d) * SEQ + st * 64 + j0;
  union { unsigned short u[8]; uint4 v; } o0, o1;
  #pragma unroll
  for (int jj = 0; jj < 8; ++jj) o0.u[jj] = t[j0 + jj][d];
  #pragma unroll
  for (int jj = 0; jj < 8; ++jj) o1.u[jj] = t[j0 + 8 + jj][d];
  *(uint4*)dst = o0.v;
  *(uint4*)(dst + 8) = o1.v;
}

// ---------------- MFMA flash attention, 4-way KV-split per q-tile ----------
__global__ __launch_bounds__(256) void k_attn(const unsigned short* __restrict__ qkv,
                                              const unsigned short* __restrict__ vt,
                                              unsigned short* __restrict__ attO) {
  __shared__ float sm[4][16], sl[4][16], so[4][64][17];
  int bid = blockIdx.x;
  int qt = (SEQ / 16 - 1) - (bid & 63);       // big q-tiles first (load balance)
  int h = (bid >> 6) % NHEAD;
  int b = bid / (64 * NHEAD);
  int tid = threadIdx.x, lane = tid & 63, wid = tid >> 6;
  int fr = lane & 15, fq = lane >> 4;
  int qb = qt * 16;

  size_t rowQ = (size_t)(b * SEQ + qb + fr) * QKVD + h * 64;
  bf16x8 bq0 = *(const bf16x8*)(qkv + rowQ + fq * 8);
  bf16x8 bq1 = *(const bf16x8*)(qkv + rowQ + 32 + fq * 8);

  float m = -1e30f, ll = 0.0f;
  f32x4 o[4] = {};
  int nkt = (qt >> 1) + 1;
  size_t kvrow0 = (size_t)(b * SEQ) * QKVD;
  const unsigned short* vbase0 = vt + ((size_t)(b * D_MODEL) + h * 64 + fr) * SEQ;

  for (int kt = wid; kt < nkt; kt += 4) {
    int kvb = kt * 32;
    bool diag = (kt == nkt - 1);
    float p[2][4];
    float tm = -1e30f;
    #pragma unroll
    for (int t = 0; t < 2; ++t) {
      size_t rowK = kvrow0 + (size_t)(kvb + t * 16 + fr) * QKVD + D_MODEL + h * 64;
      bf16x8 ak0 = *(const bf16x8*)(qkv + rowK + fq * 8);
      bf16x8 ak1 = *(const bf16x8*)(qkv + rowK + 32 + fq * 8);
      f32x4 st = {};
      st = __builtin_amdgcn_mfma_f32_16x16x32_bf16(ak0, bq0, st, 0, 0, 0);
      st = __builtin_amdgcn_mfma_f32_16x16x32_bf16(ak1, bq1, st, 0, 0, 0);
      #pragma unroll
      for (int j = 0; j < 4; ++j) {
        float s = st[j] * 0.125f;                       // 1/sqrt(64)
        if (diag && (kvb + t * 16 + fq * 4 + j > qb + fr)) s = -1e30f;
        p[t][j] = s;
        tm = fmaxf(tm, s);
      }
    }
    tm = fmaxf(tm, __shfl_xor(tm, 16));
    tm = fmaxf(tm, __shfl_xor(tm, 32));
    float mnew = fmaxf(m, tm);
    float corr = __expf(m - mnew);
    float psum = 0.0f;
    #pragma unroll
    for (int t = 0; t < 2; ++t)
      #pragma unroll
      for (int j = 0; j < 4; ++j) { float e = __expf(p[t][j] - mnew); p[t][j] = e; psum += e; }
    psum += __shfl_xor(psum, 16);
    psum += __shfl_xor(psum, 32);
    ll = ll * corr + psum;
    m = mnew;
    #pragma unroll
    for (int dg = 0; dg < 4; ++dg) {
      o[dg][0] *= corr; o[dg][1] *= corr; o[dg][2] *= corr; o[dg][3] *= corr;
    }
    unsigned int lo0 = (unsigned)f2bf(p[0][0]) | ((unsigned)f2bf(p[0][1]) << 16);
    unsigned int hi0 = (unsigned)f2bf(p[0][2]) | ((unsigned)f2bf(p[0][3]) << 16);
    unsigned int lo1 = (unsigned)f2bf(p[1][0]) | ((unsigned)f2bf(p[1][1]) << 16);
    unsigned int hi1 = (unsigned)f2bf(p[1][2]) | ((unsigned)f2bf(p[1][3]) << 16);
    int sA = fr + 16 * ((fq & 1) * 2);
    int sB = sA + 16;
    unsigned int w0a = __shfl(lo0, sA), w0b = __shfl(lo1, sA);
    unsigned int w1a = __shfl(hi0, sA), w1b = __shfl(hi1, sA);
    unsigned int w2a = __shfl(lo0, sB), w2b = __shfl(lo1, sB);
    unsigned int w3a = __shfl(hi0, sB), w3b = __shfl(hi1, sB);
    bool t1 = (fq >> 1) != 0;
    uint4 pw;
    pw.x = t1 ? w0b : w0a;
    pw.y = t1 ? w1b : w1a;
    pw.z = t1 ? w2b : w2a;
    pw.w = t1 ? w3b : w3a;
    bf16x8 pb = __builtin_bit_cast(bf16x8, pw);
    const unsigned short* vp = vbase0 + kvb + fq * 8;
    #pragma unroll
    for (int dg = 0; dg < 4; ++dg) {
      bf16x8 va = *(const bf16x8*)(vp + (size_t)dg * 16 * SEQ);
      o[dg] = __builtin_amdgcn_mfma_f32_16x16x32_bf16(va, pb, o[dg], 0, 0, 0);
    }
  }

  // ---- merge the 4 per-wave partials (online-softmax combine) ----
  if (fq == 0) { sm[wid][fr] = m; sl[wid][fr] = ll; }
  #pragma unroll
  for (int dg = 0; dg < 4; ++dg)
    #pragma unroll
    for (int j = 0; j < 4; ++j) so[wid][lane][dg * 4 + j] = o[dg][j];
  __syncthreads();
  if (wid != 0) return;
  float M = fmaxf(fmaxf(sm[0][fr], sm[1][fr]), fmaxf(sm[2][fr], sm[3][fr]));
  float e0 = __expf(sm[0][fr] - M), e1 = __expf(sm[1][fr] - M);
  float e2 = __expf(sm[2][fr] - M), e3 = __expf(sm[3][fr] - M);
  float L = sl[0][fr] * e0 + sl[1][fr] * e1 + sl[2][fr] * e2 + sl[3][fr] * e3;
  float inv = 1.0f / L;
  size_t obase = (size_t)(b * SEQ + qb + fr) * D_MODEL + h * 64;
  #pragma unroll
  for (int dg = 0; dg < 4; ++dg)
    #pragma unroll
    for (int j = 0; j < 4; ++j) {
      int k = dg * 4 + j;
      float v = (so[0][lane][k] * e0 + so[1][lane][k] * e1 +
                 so[2][lane][k] * e2 + so[3][lane][k] * e3) * inv;
      attO[obase + dg * 16 + fq * 4 + j] = f2bf(v);
    }
}

// ---------------- bf16 GEMM 128x128 (m97 structure) — small-N GEMMs --------
template<int HAS_BIAS, int DO_GELU, int HAS_RES, int OUT_BF16>
__global__ __launch_bounds__(256) void k_gemm(const unsigned short* __restrict__ A,
                                              const unsigned short* __restrict__ W,
                                              const float* __restrict__ bias,
                                              const float* __restrict__ res,
                                              void* __restrict__ Cout,
                                              int N, int K) {
  __shared__ __align__(1024) unsigned short As[128 * 64];
  __shared__ __align__(1024) unsigned short Ws[128 * 64];
  int tid = threadIdx.x, lane = tid & 63, wv = tid >> 6;
  int fr = lane & 15, fq = lane >> 4;
  int wm = wv >> 1, wn = wv & 1;

  int cpx = gridDim.x >> 3;
  int id = (blockIdx.x & 7) * cpx + (blockIdx.x >> 3);
  int bm = (id & 15) * 128;
  int bn = (id >> 4) * 128;

  const unsigned short* pA[4];
  const unsigned short* pW[4];
  unsigned short* ldsA[4];
  unsigned short* ldsW[4];
  #pragma unroll
  for (int i = 0; i < 4; ++i) {
    int c = wv * 4 + i;
    int r = c * 8 + (lane >> 3);
    int up = (lane & 7) ^ (r & 7);
    pA[i] = A + (size_t)(bm + r) * K + up * 8;
    int wr = bn + r; if (wr > N - 1) wr = N - 1;
    pW[i] = W + (size_t)wr * K + up * 8;
    ldsA[i] = &As[c * 512];
    ldsW[i] = &Ws[c * 512];
  }

  const unsigned short* aB = As + (wm * 64 + fr) * 64;
  const unsigned short* wB = Ws + (wn * 64 + fr) * 64;
  int sz = fr & 7;
  int u0 = (fq ^ sz) * 8;
  int u1 = ((4 + fq) ^ sz) * 8;

  f32x4 acc[4][4] = {};

  for (int k0 = 0; k0 < K; k0 += 64) {
    #pragma unroll
    for (int i = 0; i < 4; ++i) {
      __builtin_amdgcn_global_load_lds(
          (const __attribute__((address_space(1))) unsigned int*)(pA[i] + k0),
          (__attribute__((address_space(3))) unsigned int*)ldsA[i], 16, 0, 0);
      __builtin_amdgcn_global_load_lds(
          (const __attribute__((address_space(1))) unsigned int*)(pW[i] + k0),
          (__attribute__((address_space(3))) unsigned int*)ldsW[i], 16, 0, 0);
    }
    __syncthreads();

    bf16x8 af[4][2], bf[4][2];
    #pragma unroll
    for (int mm = 0; mm < 4; ++mm) {
      af[mm][0] = *(const bf16x8*)(aB + mm * 1024 + u0);
      af[mm][1] = *(const bf16x8*)(aB + mm * 1024 + u1);
    }
    #pragma unroll
    for (int nn = 0; nn < 4; ++nn) {
      bf[nn][0] = *(const bf16x8*)(wB + nn * 1024 + u0);
      bf[nn][1] = *(const bf16x8*)(wB + nn * 1024 + u1);
    }
    #pragma unroll
    for (int mm = 0; mm < 4; ++mm)
      #pragma unroll
      for (int nn = 0; nn < 4; ++nn) {
        acc[mm][nn] = __builtin_amdgcn_mfma_f32_16x16x32_bf16(af[mm][0], bf[nn][0], acc[mm][nn], 0, 0, 0);
        acc[mm][nn] = __builtin_amdgcn_mfma_f32_16x16x32_bf16(af[mm][1], bf[nn][1], acc[mm][nn], 0, 0, 0);
      }
    __syncthreads();
  }

  #pragma unroll
  for (int nn = 0; nn < 4; ++nn) {
    int col = bn + wn * 64 + nn * 16 + fr;
    if (col >= N) continue;
    float bv = HAS_BIAS ? bias[col] : 0.0f;
    #pragma unroll
    for (int mm = 0; mm < 4; ++mm) {
      #pragma unroll
      for (int j = 0; j < 4; ++j) {
        int row = bm + wm * 64 + mm * 16 + fq * 4 + j;
        size_t idx = (size_t)row * N + col;
        float v = acc[mm][nn][j] + bv;
        if (DO_GELU) v = 0.5f * v * (1.0f + erff(v * 0.70710678118f));
        if (HAS_RES) v += res[idx];
        if (OUT_BF16) ((unsigned short*)Cout)[idx] = f2bf(v);
        else          ((float*)Cout)[idx] = v;
      }
    }
  }
}

// ---------------- wide bf16 GEMM 128x256 (same 2-barrier structure) --------
// 8 waves (2M x 4N), each 64x64 -> per-K-iter fixed costs (barrier drains,
// ds_read latency) amortized over 2x MFMA work. LDS 48KB (A 16K + B 32K).
template<int HAS_BIAS, int DO_GELU, int OUT_BF16>
__global__ __launch_bounds__(512) void k_gemmW(const unsigned short* __restrict__ A,
                                               const unsigned short* __restrict__ W,
                                               const float* __restrict__ bias,
                                               void* __restrict__ Cout,
                                               int N, int K) {
  __shared__ __align__(1024) unsigned short As[128 * 64];   // 16 KB
  __shared__ __align__(1024) unsigned short Ws[256 * 64];   // 32 KB
  int tid = threadIdx.x, lane = tid & 63, wv = tid >> 6;    // 8 waves
  int fr = lane & 15, fq = lane >> 4;
  int wm = wv >> 2, wn = wv & 3;                            // 2M x 4N

  int cpx = gridDim.x >> 3;                                 // grid % 8 == 0
  int id = (blockIdx.x & 7) * cpx + (blockIdx.x >> 3);
  int bm = (id & 15) * 128;                                 // M fastest
  int bn = (id >> 4) * 256;

  // staging: A = 16 chunks of 1KB (wave w: 2w, 2w+1); B = 32 chunks (4w..4w+3)
  const unsigned short* pA[2];
  const unsigned short* pW[4];
  unsigned short* ldsA[2];
  unsigned short* ldsW[4];
  int srow = lane >> 3;
  int up = (lane & 7) ^ srow;                               // (row&7) == srow
  #pragma unroll
  for (int i = 0; i < 2; ++i) {
    int c = wv * 2 + i;
    pA[i] = A + (size_t)(bm + c * 8 + srow) * K + up * 8;
    ldsA[i] = &As[c * 512];
  }
  #pragma unroll
  for (int i = 0; i < 4; ++i) {
    int c = wv * 4 + i;
    int wr = bn + c * 8 + srow; if (wr > N - 1) wr = N - 1;
    pW[i] = W + (size_t)wr * K + up * 8;
    ldsW[i] = &Ws[c * 512];
  }

  const unsigned short* aB = As + (wm * 64 + fr) * 64;
  const unsigned short* wB = Ws + (wn * 64 + fr) * 64;
  int sz = fr & 7;
  int u0 = (fq ^ sz) * 8;
  int u1 = ((4 + fq) ^ sz) * 8;

  f32x4 acc[4][4] = {};

  for (int k0 = 0; k0 < K; k0 += 64) {
    #pragma unroll
    for (int i = 0; i < 2; ++i)
      __builtin_amdgcn_global_load_lds(
          (const __attribute__((address_space(1))) unsigned int*)(pA[i] + k0),
          (__attribute__((address_space(3))) unsigned int*)ldsA[i], 16, 0, 0);
    #pragma unroll
    for (int i = 0; i < 4; ++i)
      __builtin_amdgcn_global_load_lds(
          (const __attribute__((address_space(1))) unsigned int*)(pW[i] + k0),
          (__attribute__((address_space(3))) unsigned int*)ldsW[i], 16, 0, 0);
    __syncthreads();

    bf16x8 af[4][2], bf[4][2];
    #pragma unroll
    for (int mm = 0; mm < 4; ++mm) {
      af[mm][0] = *(const bf16x8*)(aB + mm * 1024 + u0);
      af[mm][1] = *(const bf16x8*)(aB + mm * 1024 + u1);
    }
    #pragma unroll
    for (int nn = 0; nn < 4; ++nn) {
      bf[nn][0] = *(const bf16x8*)(wB + nn * 1024 + u0);
      bf[nn][1] = *(const bf16x8*)(wB + nn * 1024 + u1);
    }
    #pragma unroll
    for (int mm = 0; mm < 4; ++mm)
      #pragma unroll
      for (int nn = 0; nn < 4; ++nn) {
        acc[mm][nn] = __builtin_amdgcn_mfma_f32_16x16x32_bf16(af[mm][0], bf[nn][0], acc[mm][nn], 0, 0, 0);
        acc[mm][nn] = __builtin_amdgcn_mfma_f32_16x16x32_bf16(af[mm][1], bf[nn][1], acc[mm][nn], 0, 0, 0);
      }
    __syncthreads();
  }

  #pragma unroll
  for (int nn = 0; nn < 4; ++nn) {
    int col = bn + wn * 64 + nn * 16 + fr;
    if (col >= N) continue;
    float bv = HAS_BIAS ? bias[col] : 0.0f;
    #pragma unroll
    for (int mm = 0; mm < 4; ++mm) {
      #pragma unroll
      for (int j = 0; j < 4; ++j) {
        int row = bm + wm * 64 + mm * 16 + fq * 4 + j;
        size_t idx = (size_t)row * N + col;
        float v = acc[mm][nn][j] + bv;
        if (DO_GELU) v = 0.5f * v * (1.0f + erff(v * 0.70710678118f));
        if (OUT_BF16) ((unsigned short*)Cout)[idx] = f2bf(v);
        else          ((float*)Cout)[idx] = v;
      }
    }
  }
}

// ---------------- launch ----------------
extern "C" void kernel_launch(void* const* d_in, const int* in_sizes, int n_in,
                              void* d_out, int out_size, void* d_ws, size_t ws_size,
                              hipStream_t stream) {
  const int*   ids    = (const int*)d_in[0];
  const float* tok    = (const float*)d_in[1];
  const float* pos    = (const float*)d_in[2];
  const float* ln1_w  = (const float*)d_in[3];
  const float* ln1_b  = (const float*)d_in[4];
  const float* qkv_w  = (const float*)d_in[5];
  const float* qkv_b  = (const float*)d_in[6];
  const float* out_w  = (const float*)d_in[7];
  const float* out_b  = (const float*)d_in[8];
  const float* ln2_w  = (const float*)d_in[9];
  const float* ln2_b  = (const float*)d_in[10];
  const float* fc1_w  = (const float*)d_in[11];
  const float* fc1_b  = (const float*)d_in[12];
  const float* fc2_w  = (const float*)d_in[13];
  const float* fc2_b  = (const float*)d_in[14];
  const float* lnf_w  = (const float*)d_in[15];
  const float* lnf_b  = (const float*)d_in[16];

  char* ws = (char*)d_ws;
  float*          x    = (float*)(ws);                         // 6,291,456
  unsigned short* qkvb = (unsigned short*)(ws + 6291456);      // 9,437,184
  unsigned short* h    = (unsigned short*)(ws + 15728640);     // 3,145,728 (vt during attn)
  unsigned short* attO = (unsigned short*)(ws + 18874368);     // 3,145,728
  unsigned short* gbuf = (unsigned short*)(ws + 22020096);     // 12,582,912
  unsigned short* wq   = (unsigned short*)(ws + 34603008);     // 14,155,776
  unsigned short* wo   = (unsigned short*)(ws + 48758784);     //  4,718,592
  unsigned short* w1   = (unsigned short*)(ws + 53477376);     // 18,874,368
  unsigned short* w2   = (unsigned short*)(ws + 72351744);     // 18,874,368
  unsigned short* wtok = (unsigned short*)(ws + 91226112);     // 77,194,752
  float* logits = (float*)d_out;

  // weight conversions, one launch
  {
    int n0 = NLAYER * QKVD * D_MODEL / 8;      //   884,736
    int n1 = NLAYER * D_MODEL * D_MODEL / 8;   //   294,912
    int n2 = NLAYER * FFDIM * D_MODEL / 8;     // 1,179,648
    int n3 = n2;
    int n4 = VOCAB * D_MODEL / 8;              // 4,824,672
    int tot = n0 + n1 + n2 + n3 + n4;
    k_cvt5<<<(tot + 255) / 256, 256, 0, stream>>>(
        qkv_w, wq, n0, out_w, wo, n1, fc1_w, w1, n2, fc2_w, w2, n3, tok, wtok, n4);
  }

  k_embed<<<NTOK * 192 / 256, 256, 0, stream>>>(ids, tok, pos, x);

  for (int l = 0; l < NLAYER; ++l) {
    k_ln<<<NTOK, 256, 0, stream>>>(x, ln1_w + l * D_MODEL, ln1_b + l * D_MODEL, h);
    k_gemmW<1, 0, 1><<<16 * (QKVD / 256), 512, 0, stream>>>(
        h, wq + (size_t)l * QKVD * D_MODEL, qkv_b + l * QKVD, qkvb, QKVD, D_MODEL);
    k_vt<<<2 * NHEAD * 16, 256, 0, stream>>>(qkvb, h);   // h reused as vt
    k_attn<<<2 * NHEAD * (SEQ / 16), 256, 0, stream>>>(qkvb, h, attO);
    k_gemm<1, 0, 1, 0><<<16 * (D_MODEL / 128), 256, 0, stream>>>(
        attO, wo + (size_t)l * D_MODEL * D_MODEL, out_b + l * D_MODEL, x, x, D_MODEL, D_MODEL);
    k_ln<<<NTOK, 256, 0, stream>>>(x, ln2_w + l * D_MODEL, ln2_b + l * D_MODEL, h);
    k_gemmW<1, 1, 1><<<16 * (FFDIM / 256), 512, 0, stream>>>(
        h, w1 + (size_t)l * FFDIM * D_MODEL, fc1_b + l * FFDIM, gbuf, FFDIM, D_MODEL);
    k_gemm<1, 0, 1, 0><<<16 * (D_MODEL / 128), 256, 0, stream>>>(
        gbuf, w2 + (size_t)l * D_MODEL * FFDIM, fc2_b + l * D_MODEL, x, x, D_MODEL, FFDIM);
  }

  k_ln<<<NTOK, 256, 0, stream>>>(x, lnf_w, lnf_b, h);
  // lm_head: logits = h @ tok_bf16^T  (128x256 tiles: 16 M x 197 N = 3152)
  k_gemmW<0, 0, 0><<<16 * ((VOCAB + 255) / 256), 512, 0, stream>>>(
      h, wtok, nullptr, logits, VOCAB, D_MODEL);
}

// Round 10
// 1182.976 us; speedup vs baseline: 1.0470x; 1.0470x over previous
//
#include <hip/hip_runtime.h>
#include <cstdint>
#include <cstddef>

// GPT-2: L=4, B=2, S=1024, D=768, H=12, HD=64, FF=3072, V=50257
#define D_MODEL 768
#define NHEAD   12
#define SEQ     1024
#define NTOK    2048
#define FFDIM   3072
#define NLAYER  4
#define VOCAB   50257
#define QKVD    2304

typedef float f32x4 __attribute__((ext_vector_type(4)));
typedef __bf16 bf16x8 __attribute__((ext_vector_type(8)));

__device__ __forceinline__ unsigned short f2bf(float f) {
  unsigned int u = __float_as_uint(f);
  return (unsigned short)((u + 0x7FFFu + ((u >> 16) & 1u)) >> 16);
}

// ---------------- fp32 -> bf16 bulk convert, all 5 weights in one launch ----
__global__ __launch_bounds__(256) void k_cvt5(const float* __restrict__ s0, unsigned short* __restrict__ d0, int n0,
                                              const float* __restrict__ s1, unsigned short* __restrict__ d1, int n1,
                                              const float* __restrict__ s2, unsigned short* __restrict__ d2, int n2,
                                              const float* __restrict__ s3, unsigned short* __restrict__ d3, int n3,
                                              const float* __restrict__ s4, unsigned short* __restrict__ d4, int n4) {
  int off = blockIdx.x * 256 + threadIdx.x;
  const float* s; unsigned short* d;
  if (off < n0) { s = s0; d = d0; }
  else { off -= n0; if (off < n1) { s = s1; d = d1; }
  else { off -= n1; if (off < n2) { s = s2; d = d2; }
  else { off -= n2; if (off < n3) { s = s3; d = d3; }
  else { off -= n3; if (off >= n4) return; s = s4; d = d4; } } } }
  float4 a = ((const float4*)s)[2 * off], b = ((const float4*)s)[2 * off + 1];
  union { unsigned short u[8]; uint4 v; } r;
  r.u[0] = f2bf(a.x); r.u[1] = f2bf(a.y); r.u[2] = f2bf(a.z); r.u[3] = f2bf(a.w);
  r.u[4] = f2bf(b.x); r.u[5] = f2bf(b.y); r.u[6] = f2bf(b.z); r.u[7] = f2bf(b.w);
  ((uint4*)d)[off] = r.v;
}

// ---------------- embedding: x = tok_emb[ids] + pos_emb (fp32) -------------
__global__ __launch_bounds__(256) void k_embed(const int* __restrict__ ids,
                                               const float* __restrict__ tok,
                                               const float* __restrict__ pos,
                                               float* __restrict__ x) {
  int gid = blockIdx.x * 256 + threadIdx.x;   // NTOK*192 float4s
  int t = gid / 192, f = gid - t * 192;
  int id = ids[t];
  float4 a = ((const float4*)tok)[(size_t)id * 192 + f];
  float4 b = ((const float4*)pos)[(size_t)(t & (SEQ - 1)) * 192 + f];
  float4 o; o.x = a.x + b.x; o.y = a.y + b.y; o.z = a.z + b.z; o.w = a.w + b.w;
  ((float4*)x)[gid] = o;
}

// ---------------- LayerNorm: fp32 in, bf16 out ----------------
__global__ __launch_bounds__(256) void k_ln(const float* __restrict__ x,
                                            const float* __restrict__ w,
                                            const float* __restrict__ b,
                                            unsigned short* __restrict__ out) {
  __shared__ float red[256];
  int row = blockIdx.x, tid = threadIdx.x;
  const float* xr = x + (size_t)row * D_MODEL;
  float v0 = xr[tid], v1 = xr[tid + 256], v2 = xr[tid + 512];
  red[tid] = v0 + v1 + v2;
  __syncthreads();
  for (int o = 128; o > 0; o >>= 1) { if (tid < o) red[tid] += red[tid + o]; __syncthreads(); }
  float mean = red[0] * (1.0f / 768.0f);
  __syncthreads();
  float d0 = v0 - mean, d1 = v1 - mean, d2 = v2 - mean;
  red[tid] = d0 * d0 + d1 * d1 + d2 * d2;
  __syncthreads();
  for (int o = 128; o > 0; o >>= 1) { if (tid < o) red[tid] += red[tid + o]; __syncthreads(); }
  float rstd = rsqrtf(red[0] * (1.0f / 768.0f) + 1e-5f);
  unsigned short* orow = out + (size_t)row * D_MODEL;
  orow[tid]       = f2bf(d0 * rstd * w[tid]       + b[tid]);
  orow[tid + 256] = f2bf(d1 * rstd * w[tid + 256] + b[tid + 256]);
  orow[tid + 512] = f2bf(d2 * rstd * w[tid + 512] + b[tid + 512]);
}

// ---------------- V transpose: vt[b*768 + hd][s] = V[b,s,hd] ----------------
__global__ __launch_bounds__(256) void k_vt(const unsigned short* __restrict__ qkv,
                                            unsigned short* __restrict__ vt) {
  __shared__ unsigned short t[64][80];
  int bid = blockIdx.x;                       // 2*12*16 = 384
  int st = bid & 15, h = (bid >> 4) % NHEAD, b = bid / (16 * NHEAD);
  int tid = threadIdx.x;
  int r = tid >> 2, cq = (tid & 3) * 16;
  const unsigned short* src =
      qkv + (size_t)(b * SEQ + st * 64 + r) * QKVD + 2 * D_MODEL + h * 64 + cq;
  *(uint4*)&t[r][cq] = *(const uint4*)src;
  *(uint4*)&t[r][cq + 8] = *(const uint4*)(src + 8);
  __syncthreads();
  int d = r, j0 = cq;
  unsigned short* dst = vt + ((size_t)(b * D_MODEL) + h * 64 + d) * SEQ + st * 64 + j0;
  union { unsigned short u[8]; uint4 v; } o0, o1;
  #pragma unroll
  for (int jj = 0; jj < 8; ++jj) o0.u[jj] = t[j0 + jj][d];
  #pragma unroll
  for (int jj = 0; jj < 8; ++jj) o1.u[jj] = t[j0 + 8 + jj][d];
  *(uint4*)dst = o0.v;
  *(uint4*)(dst + 8) = o1.v;
}

// ---------------- MFMA flash attention, 4-way KV-split per q-tile ----------
__global__ __launch_bounds__(256) void k_attn(const unsigned short* __restrict__ qkv,
                                              const unsigned short* __restrict__ vt,
                                              unsigned short* __restrict__ attO) {
  __shared__ float sm[4][16], sl[4][16], so[4][64][17];
  int bid = blockIdx.x;
  int qt = (SEQ / 16 - 1) - (bid & 63);       // big q-tiles first (load balance)
  int h = (bid >> 6) % NHEAD;
  int b = bid / (64 * NHEAD);
  int tid = threadIdx.x, lane = tid & 63, wid = tid >> 6;
  int fr = lane & 15, fq = lane >> 4;
  int qb = qt * 16;

  size_t rowQ = (size_t)(b * SEQ + qb + fr) * QKVD + h * 64;
  bf16x8 bq0 = *(const bf16x8*)(qkv + rowQ + fq * 8);
  bf16x8 bq1 = *(const bf16x8*)(qkv + rowQ + 32 + fq * 8);

  float m = -1e30f, ll = 0.0f;
  f32x4 o[4] = {};
  int nkt = (qt >> 1) + 1;
  size_t kvrow0 = (size_t)(b * SEQ) * QKVD;
  const unsigned short* vbase0 = vt + ((size_t)(b * D_MODEL) + h * 64 + fr) * SEQ;

  for (int kt = wid; kt < nkt; kt += 4) {
    int kvb = kt * 32;
    bool diag = (kt == nkt - 1);
    float p[2][4];
    float tm = -1e30f;
    #pragma unroll
    for (int t = 0; t < 2; ++t) {
      size_t rowK = kvrow0 + (size_t)(kvb + t * 16 + fr) * QKVD + D_MODEL + h * 64;
      bf16x8 ak0 = *(const bf16x8*)(qkv + rowK + fq * 8);
      bf16x8 ak1 = *(const bf16x8*)(qkv + rowK + 32 + fq * 8);
      f32x4 st = {};
      st = __builtin_amdgcn_mfma_f32_16x16x32_bf16(ak0, bq0, st, 0, 0, 0);
      st = __builtin_amdgcn_mfma_f32_16x16x32_bf16(ak1, bq1, st, 0, 0, 0);
      #pragma unroll
      for (int j = 0; j < 4; ++j) {
        float s = st[j] * 0.125f;                       // 1/sqrt(64)
        if (diag && (kvb + t * 16 + fq * 4 + j > qb + fr)) s = -1e30f;
        p[t][j] = s;
        tm = fmaxf(tm, s);
      }
    }
    tm = fmaxf(tm, __shfl_xor(tm, 16));
    tm = fmaxf(tm, __shfl_xor(tm, 32));
    float mnew = fmaxf(m, tm);
    float corr = __expf(m - mnew);
    float psum = 0.0f;
    #pragma unroll
    for (int t = 0; t < 2; ++t)
      #pragma unroll
      for (int j = 0; j < 4; ++j) { float e = __expf(p[t][j] - mnew); p[t][j] = e; psum += e; }
    psum += __shfl_xor(psum, 16);
    psum += __shfl_xor(psum, 32);
    ll = ll * corr + psum;
    m = mnew;
    #pragma unroll
    for (int dg = 0; dg < 4; ++dg) {
      o[dg][0] *= corr; o[dg][1] *= corr; o[dg][2] *= corr; o[dg][3] *= corr;
    }
    unsigned int lo0 = (unsigned)f2bf(p[0][0]) | ((unsigned)f2bf(p[0][1]) << 16);
    unsigned int hi0 = (unsigned)f2bf(p[0][2]) | ((unsigned)f2bf(p[0][3]) << 16);
    unsigned int lo1 = (unsigned)f2bf(p[1][0]) | ((unsigned)f2bf(p[1][1]) << 16);
    unsigned int hi1 = (unsigned)f2bf(p[1][2]) | ((unsigned)f2bf(p[1][3]) << 16);
    int sA = fr + 16 * ((fq & 1) * 2);
    int sB = sA + 16;
    unsigned int w0a = __shfl(lo0, sA), w0b = __shfl(lo1, sA);
    unsigned int w1a = __shfl(hi0, sA), w1b = __shfl(hi1, sA);
    unsigned int w2a = __shfl(lo0, sB), w2b = __shfl(lo1, sB);
    unsigned int w3a = __shfl(hi0, sB), w3b = __shfl(hi1, sB);
    bool t1 = (fq >> 1) != 0;
    uint4 pw;
    pw.x = t1 ? w0b : w0a;
    pw.y = t1 ? w1b : w1a;
    pw.z = t1 ? w2b : w2a;
    pw.w = t1 ? w3b : w3a;
    bf16x8 pb = __builtin_bit_cast(bf16x8, pw);
    const unsigned short* vp = vbase0 + kvb + fq * 8;
    #pragma unroll
    for (int dg = 0; dg < 4; ++dg) {
      bf16x8 va = *(const bf16x8*)(vp + (size_t)dg * 16 * SEQ);
      o[dg] = __builtin_amdgcn_mfma_f32_16x16x32_bf16(va, pb, o[dg], 0, 0, 0);
    }
  }

  // ---- merge the 4 per-wave partials (online-softmax combine) ----
  if (fq == 0) { sm[wid][fr] = m; sl[wid][fr] = ll; }
  #pragma unroll
  for (int dg = 0; dg < 4; ++dg)
    #pragma unroll
    for (int j = 0; j < 4; ++j) so[wid][lane][dg * 4 + j] = o[dg][j];
  __syncthreads();
  if (wid != 0) return;
  float M = fmaxf(fmaxf(sm[0][fr], sm[1][fr]), fmaxf(sm[2][fr], sm[3][fr]));
  float e0 = __expf(sm[0][fr] - M), e1 = __expf(sm[1][fr] - M);
  float e2 = __expf(sm[2][fr] - M), e3 = __expf(sm[3][fr] - M);
  float L = sl[0][fr] * e0 + sl[1][fr] * e1 + sl[2][fr] * e2 + sl[3][fr] * e3;
  float inv = 1.0f / L;
  size_t obase = (size_t)(b * SEQ + qb + fr) * D_MODEL + h * 64;
  #pragma unroll
  for (int dg = 0; dg < 4; ++dg)
    #pragma unroll
    for (int j = 0; j < 4; ++j) {
      int k = dg * 4 + j;
      float v = (so[0][lane][k] * e0 + so[1][lane][k] * e1 +
                 so[2][lane][k] * e2 + so[3][lane][k] * e3) * inv;
      attO[obase + dg * 16 + fq * 4 + j] = f2bf(v);
    }
}

// ---------------- bf16 GEMM (m97 structure), MROWS x 128 tile --------------
// MROWS=128: the proven 128^2 kernel. MROWS=64: half-height tile (grid 2x)
// for the small-N out_proj/fc2 GEMMs (96 -> 192 blocks, CU starvation fix).
// lm_head path (!BIAS && !GELU && !RES && !BF16): epilogue transposes each
// 32x128 fp32 quadrant through LDS -> lane-consecutive dword stores (256B
// full lines) to kill the 1.4x write amplification of column-strided stores.
template<int HAS_BIAS, int DO_GELU, int HAS_RES, int OUT_BF16, int MROWS>
__global__ __launch_bounds__(256) void k_gemm(const unsigned short* __restrict__ A,
                                              const unsigned short* __restrict__ W,
                                              const float* __restrict__ bias,
                                              const float* __restrict__ res,
                                              void* __restrict__ Cout,
                                              int N, int K) {
  constexpr int MACC = MROWS / 32;            // acc M-fragments per wave (4|2)
  constexpr int MSH  = (MROWS == 128) ? 4 : 5;
  union Smem {
    struct { unsigned short As[MROWS * 64]; unsigned short Ws[128 * 64]; } kl;
    float tr[32][132];
  };
  __shared__ __align__(1024) Smem smem;

  int tid = threadIdx.x, lane = tid & 63, wv = tid >> 6;
  int fr = lane & 15, fq = lane >> 4;
  int wm = wv >> 1, wn = wv & 1;

  int cpx = gridDim.x >> 3;                   // all grids % 8 == 0
  int id = (blockIdx.x & 7) * cpx + (blockIdx.x >> 3);
  int bm = (id & ((1 << MSH) - 1)) * MROWS;   // M fastest
  int bn = (id >> MSH) * 128;

  const unsigned short* pA[MACC];
  const unsigned short* pW[4];
  unsigned short* ldsA[MACC];
  unsigned short* ldsW[4];
  #pragma unroll
  for (int i = 0; i < MACC; ++i) {
    int c = wv * MACC + i;
    int r = c * 8 + (lane >> 3);
    int up = (lane & 7) ^ (r & 7);
    pA[i] = A + (size_t)(bm + r) * K + up * 8;
    ldsA[i] = &smem.kl.As[c * 512];
  }
  #pragma unroll
  for (int i = 0; i < 4; ++i) {
    int c = wv * 4 + i;
    int r = c * 8 + (lane >> 3);
    int up = (lane & 7) ^ (r & 7);
    int wr = bn + r; if (wr > N - 1) wr = N - 1;
    pW[i] = W + (size_t)wr * K + up * 8;
    ldsW[i] = &smem.kl.Ws[c * 512];
  }

  const unsigned short* aB = smem.kl.As + (wm * (MROWS / 2) + fr) * 64;
  const unsigned short* wB = smem.kl.Ws + (wn * 64 + fr) * 64;
  int sz = fr & 7;
  int u0 = (fq ^ sz) * 8;
  int u1 = ((4 + fq) ^ sz) * 8;

  f32x4 acc[MACC][4] = {};

  for (int k0 = 0; k0 < K; k0 += 64) {
    #pragma unroll
    for (int i = 0; i < MACC; ++i)
      __builtin_amdgcn_global_load_lds(
          (const __attribute__((address_space(1))) unsigned int*)(pA[i] + k0),
          (__attribute__((address_space(3))) unsigned int*)ldsA[i], 16, 0, 0);
    #pragma unroll
    for (int i = 0; i < 4; ++i)
      __builtin_amdgcn_global_load_lds(
          (const __attribute__((address_space(1))) unsigned int*)(pW[i] + k0),
          (__attribute__((address_space(3))) unsigned int*)ldsW[i], 16, 0, 0);
    __syncthreads();

    bf16x8 af[MACC][2], bf[4][2];
    #pragma unroll
    for (int mm = 0; mm < MACC; ++mm) {
      af[mm][0] = *(const bf16x8*)(aB + mm * 1024 + u0);
      af[mm][1] = *(const bf16x8*)(aB + mm * 1024 + u1);
    }
    #pragma unroll
    for (int nn = 0; nn < 4; ++nn) {
      bf[nn][0] = *(const bf16x8*)(wB + nn * 1024 + u0);
      bf[nn][1] = *(const bf16x8*)(wB + nn * 1024 + u1);
    }
    #pragma unroll
    for (int mm = 0; mm < MACC; ++mm)
      #pragma unroll
      for (int nn = 0; nn < 4; ++nn) {
        acc[mm][nn] = __builtin_amdgcn_mfma_f32_16x16x32_bf16(af[mm][0], bf[nn][0], acc[mm][nn], 0, 0, 0);
        acc[mm][nn] = __builtin_amdgcn_mfma_f32_16x16x32_bf16(af[mm][1], bf[nn][1], acc[mm][nn], 0, 0, 0);
      }
    __syncthreads();
  }

  if constexpr (!HAS_BIAS && !DO_GELU && !HAS_RES && !OUT_BF16) {
    // lm_head: transpose each quadrant through LDS -> coalesced dword stores
    float* C = (float*)Cout;
    #pragma unroll
    for (int mm = 0; mm < MACC; ++mm) {
      __syncthreads();
      #pragma unroll
      for (int nn = 0; nn < 4; ++nn)
        #pragma unroll
        for (int j = 0; j < 4; ++j)
          smem.tr[wm * 16 + fq * 4 + j][wn * 64 + nn * 16 + fr] = acc[mm][nn][j];
      __syncthreads();
      #pragma unroll
      for (int e = tid; e < 32 * 128; e += 256) {
        int lr = e >> 7, lc = e & 127;
        int row = bm + (lr >> 4) * 64 + mm * 16 + (lr & 15);
        int col = bn + lc;
        if (col < N) C[(size_t)row * N + col] = smem.tr[lr][lc];
      }
    }
  } else {
    #pragma unroll
    for (int nn = 0; nn < 4; ++nn) {
      int col = bn + wn * 64 + nn * 16 + fr;
      if (col >= N) continue;
      float bv = HAS_BIAS ? bias[col] : 0.0f;
      #pragma unroll
      for (int mm = 0; mm < MACC; ++mm) {
        #pragma unroll
        for (int j = 0; j < 4; ++j) {
          int row = bm + wm * (MROWS / 2) + mm * 16 + fq * 4 + j;
          size_t idx = (size_t)row * N + col;
          float v = acc[mm][nn][j] + bv;
          if (DO_GELU) v = 0.5f * v * (1.0f + erff(v * 0.70710678118f));
          if (HAS_RES) v += res[idx];
          if (OUT_BF16) ((unsigned short*)Cout)[idx] = f2bf(v);
          else          ((float*)Cout)[idx] = v;
        }
      }
    }
  }
}

// ---------------- launch ----------------
extern "C" void kernel_launch(void* const* d_in, const int* in_sizes, int n_in,
                              void* d_out, int out_size, void* d_ws, size_t ws_size,
                              hipStream_t stream) {
  const int*   ids    = (const int*)d_in[0];
  const float* tok    = (const float*)d_in[1];
  const float* pos    = (const float*)d_in[2];
  const float* ln1_w  = (const float*)d_in[3];
  const float* ln1_b  = (const float*)d_in[4];
  const float* qkv_w  = (const float*)d_in[5];
  const float* qkv_b  = (const float*)d_in[6];
  const float* out_w  = (const float*)d_in[7];
  const float* out_b  = (const float*)d_in[8];
  const float* ln2_w  = (const float*)d_in[9];
  const float* ln2_b  = (const float*)d_in[10];
  const float* fc1_w  = (const float*)d_in[11];
  const float* fc1_b  = (const float*)d_in[12];
  const float* fc2_w  = (const float*)d_in[13];
  const float* fc2_b  = (const float*)d_in[14];
  const float* lnf_w  = (const float*)d_in[15];
  const float* lnf_b  = (const float*)d_in[16];

  char* ws = (char*)d_ws;
  float*          x    = (float*)(ws);                         // 6,291,456
  unsigned short* qkvb = (unsigned short*)(ws + 6291456);      // 9,437,184
  unsigned short* h    = (unsigned short*)(ws + 15728640);     // 3,145,728 (vt during attn)
  unsigned short* attO = (unsigned short*)(ws + 18874368);     // 3,145,728
  unsigned short* gbuf = (unsigned short*)(ws + 22020096);     // 12,582,912
  unsigned short* wq   = (unsigned short*)(ws + 34603008);     // 14,155,776
  unsigned short* wo   = (unsigned short*)(ws + 48758784);     //  4,718,592
  unsigned short* w1   = (unsigned short*)(ws + 53477376);     // 18,874,368
  unsigned short* w2   = (unsigned short*)(ws + 72351744);     // 18,874,368
  unsigned short* wtok = (unsigned short*)(ws + 91226112);     // 77,194,752
  float* logits = (float*)d_out;

  // weight conversions, one launch
  {
    int n0 = NLAYER * QKVD * D_MODEL / 8;      //   884,736
    int n1 = NLAYER * D_MODEL * D_MODEL / 8;   //   294,912
    int n2 = NLAYER * FFDIM * D_MODEL / 8;     // 1,179,648
    int n3 = n2;
    int n4 = VOCAB * D_MODEL / 8;              // 4,824,672
    int tot = n0 + n1 + n2 + n3 + n4;
    k_cvt5<<<(tot + 255) / 256, 256, 0, stream>>>(
        qkv_w, wq, n0, out_w, wo, n1, fc1_w, w1, n2, fc2_w, w2, n3, tok, wtok, n4);
  }

  k_embed<<<NTOK * 192 / 256, 256, 0, stream>>>(ids, tok, pos, x);

  for (int l = 0; l < NLAYER; ++l) {
    k_ln<<<NTOK, 256, 0, stream>>>(x, ln1_w + l * D_MODEL, ln1_b + l * D_MODEL, h);
    k_gemm<1, 0, 0, 1, 128><<<16 * (QKVD / 128), 256, 0, stream>>>(
        h, wq + (size_t)l * QKVD * D_MODEL, qkv_b + l * QKVD, nullptr, qkvb, QKVD, D_MODEL);
    k_vt<<<2 * NHEAD * 16, 256, 0, stream>>>(qkvb, h);   // h reused as vt
    k_attn<<<2 * NHEAD * (SEQ / 16), 256, 0, stream>>>(qkvb, h, attO);
    k_gemm<1, 0, 1, 0, 64><<<32 * (D_MODEL / 128), 256, 0, stream>>>(
        attO, wo + (size_t)l * D_MODEL * D_MODEL, out_b + l * D_MODEL, x, x, D_MODEL, D_MODEL);
    k_ln<<<NTOK, 256, 0, stream>>>(x, ln2_w + l * D_MODEL, ln2_b + l * D_MODEL, h);
    k_gemm<1, 1, 0, 1, 128><<<16 * (FFDIM / 128), 256, 0, stream>>>(
        h, w1 + (size_t)l * FFDIM * D_MODEL, fc1_b + l * FFDIM, nullptr, gbuf, FFDIM, D_MODEL);
    k_gemm<1, 0, 1, 0, 64><<<32 * (D_MODEL / 128), 256, 0, stream>>>(
        gbuf, w2 + (size_t)l * D_MODEL * FFDIM, fc2_b + l * D_MODEL, x, x, D_MODEL, FFDIM);
  }

  k_ln<<<NTOK, 256, 0, stream>>>(x, lnf_w, lnf_b, h);
  // lm_head: logits = h @ tok_bf16^T  (128^2 tiles, 16 M x 393 N, grid % 8 == 0)
  k_gemm<0, 0, 0, 0, 128><<<16 * ((VOCAB + 127) / 128), 256, 0, stream>>>(
      h, wtok, nullptr, nullptr, logits, VOCAB, D_MODEL);
}